// Round 7
// baseline (389.658 us; speedup 1.0000x reference)
//
#include <hip/hip_runtime.h>
#include <hip/hip_bf16.h>
#include <stdint.h>

#define LOG2E 1.4426950408889634f

typedef float f32x2 __attribute__((ext_vector_type(2)));

__device__ __forceinline__ float fast_sig(float x) {
    float e = __builtin_amdgcn_exp2f(-LOG2E * x);
    return __builtin_amdgcn_rcpf(1.0f + e);
}
__device__ __forceinline__ float fast_tanh(float x) {
    float e = __builtin_amdgcn_exp2f(2.0f * LOG2E * x);
    return 1.0f - 2.0f * __builtin_amdgcn_rcpf(e + 1.0f);
}
__device__ __forceinline__ float rl_f(float v, int k) {
    return __int_as_float(__builtin_amdgcn_readlane(__float_as_int(v), k));
}

// ---------------- K1: tables + W_hh transpose (blocks 0..63) | length count (blocks 64..2111) ----
// xproj[v][j] = float4 gate pre-acts (i,f,g,o) of unit j for char v (incl. both biases)
// hbwd[v][j]  = backward-direction output for last-char value v
// wt[k*256 + j*4 + g] = w_hh_f[(g*64+j)*64 + k]
__global__ void prep1(const float* __restrict__ emb,
                      const float* __restrict__ w_ih_f, const float* __restrict__ b_ih_f,
                      const float* __restrict__ b_hh_f,
                      const float* __restrict__ w_ih_b, const float* __restrict__ b_ih_b,
                      const float* __restrict__ b_hh_b,
                      const float* __restrict__ w_hh_f, const int* __restrict__ chars,
                      float* __restrict__ xproj, float* __restrict__ hbwd,
                      float* __restrict__ wt, int* __restrict__ cnt) {
    const int blk = blockIdx.x, tid = threadIdx.x;
    if (blk < 64) {
        int d = blk * 256 + tid;                       // W_hh transpose, one elem/thread
        int tk = d >> 8, tj = (d >> 2) & 63, tg = d & 3;
        wt[d] = w_hh_f[(((tg << 6) | tj) << 6) | tk];

        int v = blk * 4 + (tid >> 6);
        int j = tid & 63;
        float e[20];
#pragma unroll
        for (int t = 0; t < 20; ++t) e[t] = emb[v * 20 + t];
        float sf[4], sb[4];
#pragma unroll
        for (int g = 0; g < 4; ++g) {
            int row = g * 64 + j;
            float a = b_ih_f[row] + b_hh_f[row];
            float b = b_ih_b[row] + b_hh_b[row];
#pragma unroll
            for (int t = 0; t < 20; ++t) {
                a += e[t] * w_ih_f[row * 20 + t];
                b += e[t] * w_ih_b[row * 20 + t];
            }
            sf[g] = a; sb[g] = b;
        }
        ((float4*)xproj)[v * 64 + j] = make_float4(sf[0], sf[1], sf[2], sf[3]);
        float cb = fast_sig(sb[0]) * fast_tanh(sb[2]);
        hbwd[v * 64 + j] = fast_sig(sb[3]) * fast_tanh(cb);
    } else {
        int word = (blk - 64) * 8 + (tid >> 5);
        int c = tid & 31;
        int v = chars[word * 32 + c];
        unsigned long long m = __ballot(v != 0);
        int hi = (tid >> 5) & 1;
        int len = __popcll(m & (hi ? 0xFFFFFFFF00000000ULL : 0x00000000FFFFFFFFULL));
        if (c == 0 && len > 0) atomicAdd(&cnt[len], 1);
    }
}

// ---------------- K2: scatter (DESCENDING length buckets, LPT) + zero pad-word outputs ----------
// cursor0 lives 4KB away from cnt: the atomically-hammered lines must not share
// cache lines with the read-hot cnt[] prefix data (round-6: 159us of coherence stalls).
__global__ void prep2(const int* __restrict__ chars, const int* __restrict__ cnt,
                      int* __restrict__ cursor0, int* __restrict__ sorted,
                      int* __restrict__ nvp, float4* __restrict__ out4) {
    int word = blockIdx.x * 8 + (threadIdx.x >> 5);
    int c = threadIdx.x & 31;
    int v = chars[word * 32 + c];
    unsigned long long m = __ballot(v != 0);
    int hi = (threadIdx.x >> 5) & 1;
    int len = __popcll(m & (hi ? 0xFFFFFFFF00000000ULL : 0x00000000FFFFFFFFULL));
    if (len == 0) {
        out4[word * 32 + c] = make_float4(0.f, 0.f, 0.f, 0.f);   // 32 lanes x 16B = full row
    } else if (c == 0) {
        int pre = 0;
        for (int l = len + 1; l <= 32; ++l) pre += cnt[l];        // longer words first (LPT)
        int pos = pre + atomicAdd(&cursor0[len], 1);
        sorted[pos] = word;
    }
    if (word == 0 && c == 1) {
        int t = 0;
        for (int l = 1; l <= 32; ++l) t += cnt[l];
        *nvp = t;
    }
}

// ---------------- K3: forward LSTM recurrence, 8 words/wave, 512-thread blocks ----------------
// One 64KB W_hh LDS copy serves 8 waves x 8 words: per-word LDS traffic halves vs 4w/wave.
__launch_bounds__(512)
__global__ void bilstm_main(const int* __restrict__ chars, const float4* __restrict__ wtv,
                            const float4* __restrict__ xproj, const float* __restrict__ hbwd,
                            const int* __restrict__ sorted, const int* __restrict__ nvp,
                            float* __restrict__ out) {
    __shared__ float4 ldsw[4096];  // full W_hh: [k][j] float4 gates, 64KB
    const int nv = *nvp;
    if (blockIdx.x * 64 >= nv) return;  // whole block dead (uniform)
    const int tid = threadIdx.x;
    for (int i = tid; i < 4096; i += 512) ldsw[i] = wtv[i];  // linear, conflict-free
    __syncthreads();

    const int wave = tid >> 6, lane = tid & 63;
    const int base = (blockIdx.x * 8 + wave) * 8;
    const int nw = min(8, nv - base);
    if (nw <= 0) return;  // no barriers after this point

    int idv = 0;
    if (lane < 8 && base + lane < nv) idv = sorted[base + lane];

    int ch[8], len[8];
#pragma unroll
    for (int g = 0; g < 8; ++g) {
        int w = __builtin_amdgcn_readlane(idv, g);
        int c = 0;
        if (lane < 32) c = chars[w * 32 + lane];
        ch[g] = c;
        unsigned long long m = __ballot(c != 0);
        len[g] = (g < nw) ? __popcll(m) : 0;
    }
    int maxlen = 0;
#pragma unroll
    for (int g = 0; g < 8; ++g) maxlen = max(maxlen, len[g]);

    float h[8], cc[8];
#pragma unroll
    for (int g = 0; g < 8; ++g) { h[g] = 0.0f; cc[g] = 0.0f; }

    for (int t = 0; t < maxlen; ++t) {
        // acc initialized with the input-projection row (folds bias/x into the FMA chain);
        // packed as float2 pairs so the compiler can form v_pk_fma_f32
        f32x2 axy[8], azw[8];
#pragma unroll
        for (int g = 0; g < 8; ++g) {
            int ct = __builtin_amdgcn_readlane(ch[g], t);
            float4 xp = xproj[ct * 64 + lane];
            axy[g][0] = xp.x; axy[g][1] = xp.y;
            azw[g][0] = xp.z; azw[g][1] = xp.w;
        }
#pragma unroll 4
        for (int k = 0; k < 64; ++k) {
            float4 w4 = ldsw[(k << 6) + lane];
            f32x2 wxy; wxy[0] = w4.x; wxy[1] = w4.y;
            f32x2 wzw; wzw[0] = w4.z; wzw[1] = w4.w;
#pragma unroll
            for (int g = 0; g < 8; ++g) {
                float hk = rl_f(h[g], k);
                f32x2 h2; h2[0] = hk; h2[1] = hk;
                axy[g] = __builtin_elementwise_fma(h2, wxy, axy[g]);
                azw[g] = __builtin_elementwise_fma(h2, wzw, azw[g]);
            }
        }
#pragma unroll
        for (int g = 0; g < 8; ++g) {
            float gi = fast_sig(axy[g][0]);
            float gf = fast_sig(axy[g][1]);
            float gg = fast_tanh(azw[g][0]);
            float go = fast_sig(azw[g][1]);
            float cn = gf * cc[g] + gi * gg;
            float hn = go * fast_tanh(cn);
            bool act = (t < len[g]);  // wave-uniform
            cc[g] = act ? cn : cc[g];
            h[g] = act ? hn : h[g];
        }
    }

#pragma unroll
    for (int g = 0; g < 8; ++g) {
        if (g < nw) {
            int w = __builtin_amdgcn_readlane(idv, g);
            int cl = __builtin_amdgcn_readlane(ch[g], len[g] - 1);
            float hb = hbwd[cl * 64 + lane];
            out[w * 128 + lane] = h[g];
            out[w * 128 + 64 + lane] = hb;
        }
    }
}

extern "C" void kernel_launch(void* const* d_in, const int* in_sizes, int n_in,
                              void* d_out, int out_size, void* d_ws, size_t ws_size,
                              hipStream_t stream) {
    const int* chars    = (const int*)d_in[0];
    const float* emb    = (const float*)d_in[1];
    const float* w_ih_f = (const float*)d_in[2];
    const float* w_hh_f = (const float*)d_in[3];
    const float* b_ih_f = (const float*)d_in[4];
    const float* b_hh_f = (const float*)d_in[5];
    const float* w_ih_b = (const float*)d_in[6];
    // d_in[7] = w_hh_b: unused (backward runs one step from zero state)
    const float* b_ih_b = (const float*)d_in[8];
    const float* b_hh_b = (const float*)d_in[9];
    float* out = (float*)d_out;

    float* wsf   = (float*)d_ws;
    float* xproj = wsf;                    // 65536 f32 (256KB)
    float* hbwd  = wsf + 65536;            // 16384 f32
    float* wt    = wsf + 65536 + 16384;    // 16384 f32 transposed W_hh
    int* iws     = (int*)(wt + 16384);
    int* sorted  = iws;                    // 16384
    int* cnt     = iws + 16384;            // 33 (read-hot in prep2)
    int* cursor0 = iws + 17408;            // 33 (atomic-hot) — 4KB past cnt, no shared lines
    int* nv      = iws + 17472;            // 1  — own line

    (void)hipMemsetAsync(cnt, 0, 33 * sizeof(int), stream);
    (void)hipMemsetAsync(cursor0, 0, 65 * sizeof(int), stream);  // cursor0 + gap + nv
    prep1<<<2112, 256, 0, stream>>>(emb, w_ih_f, b_ih_f, b_hh_f,
                                    w_ih_b, b_ih_b, b_hh_b, w_hh_f, chars,
                                    xproj, hbwd, wt, cnt);
    prep2<<<2048, 256, 0, stream>>>(chars, cnt, cursor0, sorted, nv, (float4*)out);
    bilstm_main<<<256, 512, 0, stream>>>(chars, (const float4*)wt,
                                         (const float4*)xproj,
                                         hbwd, sorted, nv, out);
}

// Round 8
// 204.176 us; speedup vs baseline: 1.9084x; 1.9084x over previous
//
#include <hip/hip_runtime.h>
#include <hip/hip_bf16.h>
#include <stdint.h>

#define LOG2E 1.4426950408889634f

typedef float f32x2 __attribute__((ext_vector_type(2)));

__device__ __forceinline__ float fast_sig(float x) {
    float e = __builtin_amdgcn_exp2f(-LOG2E * x);
    return __builtin_amdgcn_rcpf(1.0f + e);
}
__device__ __forceinline__ float fast_tanh(float x) {
    float e = __builtin_amdgcn_exp2f(2.0f * LOG2E * x);
    return 1.0f - 2.0f * __builtin_amdgcn_rcpf(e + 1.0f);
}
__device__ __forceinline__ float rl_f(float v, int k) {
    return __int_as_float(__builtin_amdgcn_readlane(__float_as_int(v), k));
}

// ---------------- K1: tables + W_hh transpose (blocks 0..63) | length count (blocks 64..2111) ----
// xproj[v][j] = float4 gate pre-acts (i,f,g,o) of unit j for char v (incl. both biases)
// hbwd[v][j]  = backward-direction output for last-char value v
// wt[k*256 + j*4 + g] = w_hh_f[(g*64+j)*64 + k]
__global__ void prep1(const float* __restrict__ emb,
                      const float* __restrict__ w_ih_f, const float* __restrict__ b_ih_f,
                      const float* __restrict__ b_hh_f,
                      const float* __restrict__ w_ih_b, const float* __restrict__ b_ih_b,
                      const float* __restrict__ b_hh_b,
                      const float* __restrict__ w_hh_f, const int* __restrict__ chars,
                      float* __restrict__ xproj, float* __restrict__ hbwd,
                      float* __restrict__ wt, int* __restrict__ cnt) {
    const int blk = blockIdx.x, tid = threadIdx.x;
    if (blk < 64) {
        int d = blk * 256 + tid;                       // W_hh transpose, one elem/thread
        int tk = d >> 8, tj = (d >> 2) & 63, tg = d & 3;
        wt[d] = w_hh_f[(((tg << 6) | tj) << 6) | tk];

        int v = blk * 4 + (tid >> 6);
        int j = tid & 63;
        float e[20];
#pragma unroll
        for (int t = 0; t < 20; ++t) e[t] = emb[v * 20 + t];
        float sf[4], sb[4];
#pragma unroll
        for (int g = 0; g < 4; ++g) {
            int row = g * 64 + j;
            float a = b_ih_f[row] + b_hh_f[row];
            float b = b_ih_b[row] + b_hh_b[row];
#pragma unroll
            for (int t = 0; t < 20; ++t) {
                a += e[t] * w_ih_f[row * 20 + t];
                b += e[t] * w_ih_b[row * 20 + t];
            }
            sf[g] = a; sb[g] = b;
        }
        ((float4*)xproj)[v * 64 + j] = make_float4(sf[0], sf[1], sf[2], sf[3]);
        float cb = fast_sig(sb[0]) * fast_tanh(sb[2]);
        hbwd[v * 64 + j] = fast_sig(sb[3]) * fast_tanh(cb);
    } else {
        int word = (blk - 64) * 8 + (tid >> 5);
        int c = tid & 31;
        int v = chars[word * 32 + c];
        unsigned long long m = __ballot(v != 0);
        int hi = (tid >> 5) & 1;
        int len = __popcll(m & (hi ? 0xFFFFFFFF00000000ULL : 0x00000000FFFFFFFFULL));
        if (c == 0 && len > 0) atomicAdd(&cnt[len], 1);
    }
}

// ---------------- K2: scatter (DESCENDING length buckets, LPT) + zero pad-word outputs ----------
// cursor0 lives 4KB away from cnt: the atomically-hammered lines must not share
// cache lines with the read-hot cnt[] prefix data (round-6: 159us of coherence stalls).
__global__ void prep2(const int* __restrict__ chars, const int* __restrict__ cnt,
                      int* __restrict__ cursor0, int* __restrict__ sorted,
                      int* __restrict__ nvp, float4* __restrict__ out4) {
    int word = blockIdx.x * 8 + (threadIdx.x >> 5);
    int c = threadIdx.x & 31;
    int v = chars[word * 32 + c];
    unsigned long long m = __ballot(v != 0);
    int hi = (threadIdx.x >> 5) & 1;
    int len = __popcll(m & (hi ? 0xFFFFFFFF00000000ULL : 0x00000000FFFFFFFFULL));
    if (len == 0) {
        out4[word * 32 + c] = make_float4(0.f, 0.f, 0.f, 0.f);   // 32 lanes x 16B = full row
    } else if (c == 0) {
        int pre = 0;
        for (int l = len + 1; l <= 32; ++l) pre += cnt[l];        // longer words first (LPT)
        int pos = pre + atomicAdd(&cursor0[len], 1);
        sorted[pos] = word;
    }
    if (word == 0 && c == 1) {
        int t = 0;
        for (int l = 1; l <= 32; ++l) t += cnt[l];
        *nvp = t;
    }
}

// ---------------- K3: forward LSTM recurrence, 4 words/wave (round-3/6 proven structure) -------
// k=0..7 weights live in 32 VGPRs (per-lane), k=8..63 in LDS. Register budget:
// (256,2) caps at 128 VGPR; base ~88 + 32 wreg = ~120. NEVER use (256,3)/512-thr (spill: r5/r7).
__launch_bounds__(256, 2)
__global__ void bilstm_main(const int* __restrict__ chars, const float4* __restrict__ wtv,
                            const float4* __restrict__ xproj, const float* __restrict__ hbwd,
                            const int* __restrict__ sorted, const int* __restrict__ nvp,
                            float* __restrict__ out) {
    __shared__ float4 ldsw[3584];  // k=8..63: 56KB -> still 2 blocks/CU
    const int nv = *nvp;
    if (blockIdx.x * 16 >= nv) return;  // whole block dead (uniform)
    const int tid = threadIdx.x;
    for (int i = tid; i < 3584; i += 256) ldsw[i] = wtv[512 + i];  // linear, conflict-free
    __syncthreads();

    const int wave = tid >> 6, lane = tid & 63;
    const int base = (blockIdx.x * 4 + wave) * 4;
    const int nw = min(4, nv - base);
    if (nw <= 0) return;  // no barriers after this point

    // k=0..7 weights hoisted to registers (32 VGPR), L2-hot coalesced load
    float4 wreg[8];
#pragma unroll
    for (int i = 0; i < 8; ++i) wreg[i] = wtv[i * 64 + lane];

    int idv = 0;
    if (lane < 4 && base + lane < nv) idv = sorted[base + lane];

    int wid[4], ch[4], len[4];
#pragma unroll
    for (int g = 0; g < 4; ++g) {
        wid[g] = __builtin_amdgcn_readlane(idv, g);
        int c = 0;
        if (lane < 32) c = chars[wid[g] * 32 + lane];
        ch[g] = c;
        unsigned long long m = __ballot(c != 0);
        len[g] = (g < nw) ? __popcll(m) : 0;
    }
    int maxlen = 0;
#pragma unroll
    for (int g = 0; g < 4; ++g) maxlen = max(maxlen, len[g]);

    float h[4], cc[4];
#pragma unroll
    for (int g = 0; g < 4; ++g) { h[g] = 0.0f; cc[g] = 0.0f; }

    for (int t = 0; t < maxlen; ++t) {
        // acc initialized with the input-projection row (folds bias/x into the FMA chain);
        // packed as float2 pairs so the compiler can form v_pk_fma_f32
        f32x2 axy[4], azw[4];
#pragma unroll
        for (int g = 0; g < 4; ++g) {
            int ct = __builtin_amdgcn_readlane(ch[g], t);
            float4 xp = xproj[ct * 64 + lane];
            axy[g][0] = xp.x; axy[g][1] = xp.y;
            azw[g][0] = xp.z; azw[g][1] = xp.w;
        }
        // k=0..7 from registers: zero lgkm wait, covers LDS latency of the reads below
#pragma unroll
        for (int k = 0; k < 8; ++k) {
            float4 w4 = wreg[k];
            f32x2 wxy; wxy[0] = w4.x; wxy[1] = w4.y;
            f32x2 wzw; wzw[0] = w4.z; wzw[1] = w4.w;
#pragma unroll
            for (int g = 0; g < 4; ++g) {
                float hk = rl_f(h[g], k);
                f32x2 h2; h2[0] = hk; h2[1] = hk;
                axy[g] = __builtin_elementwise_fma(h2, wxy, axy[g]);
                azw[g] = __builtin_elementwise_fma(h2, wzw, azw[g]);
            }
        }
#pragma unroll 8
        for (int k = 8; k < 64; ++k) {
            float4 w4 = ldsw[((k - 8) << 6) + lane];
            f32x2 wxy; wxy[0] = w4.x; wxy[1] = w4.y;
            f32x2 wzw; wzw[0] = w4.z; wzw[1] = w4.w;
#pragma unroll
            for (int g = 0; g < 4; ++g) {
                float hk = rl_f(h[g], k);
                f32x2 h2; h2[0] = hk; h2[1] = hk;
                axy[g] = __builtin_elementwise_fma(h2, wxy, axy[g]);
                azw[g] = __builtin_elementwise_fma(h2, wzw, azw[g]);
            }
        }
#pragma unroll
        for (int g = 0; g < 4; ++g) {
            float gi = fast_sig(axy[g][0]);
            float gf = fast_sig(axy[g][1]);
            float gg = fast_tanh(azw[g][0]);
            float go = fast_sig(azw[g][1]);
            float cn = gf * cc[g] + gi * gg;
            float hn = go * fast_tanh(cn);
            bool act = (t < len[g]);  // wave-uniform
            cc[g] = act ? cn : cc[g];
            h[g] = act ? hn : h[g];
        }
    }

#pragma unroll
    for (int g = 0; g < 4; ++g) {
        if (g < nw) {
            int cl = __builtin_amdgcn_readlane(ch[g], len[g] - 1);
            float hb = hbwd[cl * 64 + lane];
            out[wid[g] * 128 + lane] = h[g];
            out[wid[g] * 128 + 64 + lane] = hb;
        }
    }
}

extern "C" void kernel_launch(void* const* d_in, const int* in_sizes, int n_in,
                              void* d_out, int out_size, void* d_ws, size_t ws_size,
                              hipStream_t stream) {
    const int* chars    = (const int*)d_in[0];
    const float* emb    = (const float*)d_in[1];
    const float* w_ih_f = (const float*)d_in[2];
    const float* w_hh_f = (const float*)d_in[3];
    const float* b_ih_f = (const float*)d_in[4];
    const float* b_hh_f = (const float*)d_in[5];
    const float* w_ih_b = (const float*)d_in[6];
    // d_in[7] = w_hh_b: unused (backward runs one step from zero state)
    const float* b_ih_b = (const float*)d_in[8];
    const float* b_hh_b = (const float*)d_in[9];
    float* out = (float*)d_out;

    float* wsf   = (float*)d_ws;
    float* xproj = wsf;                    // 65536 f32 (256KB)
    float* hbwd  = wsf + 65536;            // 16384 f32
    float* wt    = wsf + 65536 + 16384;    // 16384 f32 transposed W_hh
    int* iws     = (int*)(wt + 16384);
    int* sorted  = iws;                    // 16384
    int* cnt     = iws + 16384;            // 33 (read-hot in prep2)
    int* cursor0 = iws + 17408;            // 33 (atomic-hot) — 4KB past cnt, no shared lines
    int* nv      = iws + 17472;            // 1  — own line

    (void)hipMemsetAsync(cnt, 0, 33 * sizeof(int), stream);
    (void)hipMemsetAsync(cursor0, 0, 65 * sizeof(int), stream);  // cursor0 + gap + nv
    prep1<<<2112, 256, 0, stream>>>(emb, w_ih_f, b_ih_f, b_hh_f,
                                    w_ih_b, b_ih_b, b_hh_b, w_hh_f, chars,
                                    xproj, hbwd, wt, cnt);
    prep2<<<2048, 256, 0, stream>>>(chars, cnt, cursor0, sorted, nv, (float4*)out);
    bilstm_main<<<1024, 256, 0, stream>>>(chars, (const float4*)wt,
                                          (const float4*)xproj,
                                          hbwd, sorted, nv, out);
}